// Round 1
// baseline (666.827 us; speedup 1.0000x reference)
//
#include <hip/hip_runtime.h>
#include <stdint.h>

#define C_CLASSES 1024
#define D_DIM     512
#define N_SUP     65536
#define N_QRY     65536

typedef float f32x4 __attribute__((ext_vector_type(4)));
typedef short bf16x8 __attribute__((ext_vector_type(8)));
typedef unsigned short u16x4 __attribute__((ext_vector_type(4)));
typedef unsigned short u16x8 __attribute__((ext_vector_type(8)));

// f32 -> bf16 with round-to-nearest-even (manual, header-independent)
__device__ inline unsigned short f2bf(float f) {
    union { float f; unsigned int u; } x; x.f = f;
    unsigned int u = x.u;
    unsigned int r = (u + 0x7fffu + ((u >> 16) & 1u)) >> 16;
    return (unsigned short)r;
}

// ---------------------------------------------------------------------------
// Kernel 1: per-class prototypes. One block per class; 4 waves scan disjoint
// row ranges via ballot; register accumulators (8 f32/lane); LDS combine.
// Emits protos as bf16 [C][D] (B^T layout for the GEMM) and p_sq f32 [C].
// ---------------------------------------------------------------------------
__global__ __launch_bounds__(256) void proto_kernel(
    const float* __restrict__ zs, const int* __restrict__ ys,
    unsigned short* __restrict__ protos, float* __restrict__ psq)
{
    const int c    = blockIdx.x;
    const int tid  = threadIdx.x;
    const int w    = tid >> 6;
    const int lane = tid & 63;

    f32x4 s0 = {0.f, 0.f, 0.f, 0.f};
    f32x4 s1 = {0.f, 0.f, 0.f, 0.f};
    int cnt = 0;

    const int rowsPerWave = N_SUP / 4;
    const int base0 = w * rowsPerWave;
    for (int base = base0; base < base0 + rowsPerWave; base += 64) {
        int lab = ys[base + lane];
        unsigned long long mask = __ballot(lab == c);
        cnt += __popcll(mask);
        while (mask) {
            int b = __builtin_ctzll(mask);
            mask &= mask - 1;
            const f32x4* zp = (const f32x4*)(zs + (size_t)(base + b) * D_DIM);
            s0 += zp[lane];
            s1 += zp[64 + lane];
        }
    }

    __shared__ float sAcc[4][D_DIM];
    __shared__ int   sCnt[4];
    ((f32x4*)&sAcc[w][0])[lane]      = s0;
    ((f32x4*)&sAcc[w][0])[64 + lane] = s1;
    if (lane == 0) sCnt[w] = cnt;
    __syncthreads();

    float tot = (float)(sCnt[0] + sCnt[1] + sCnt[2] + sCnt[3]);
    float inv = 1.0f / fmaxf(tot, 1.0f);
    int t2 = tid + 256;
    float p0 = (sAcc[0][tid] + sAcc[1][tid] + sAcc[2][tid] + sAcc[3][tid]) * inv;
    float p1 = (sAcc[0][t2]  + sAcc[1][t2]  + sAcc[2][t2]  + sAcc[3][t2])  * inv;
    protos[(size_t)c * D_DIM + tid] = f2bf(p0);
    protos[(size_t)c * D_DIM + t2]  = f2bf(p1);

    float ps = p0 * p0 + p1 * p1;
    #pragma unroll
    for (int off = 32; off > 0; off >>= 1) ps += __shfl_down(ps, off, 64);
    __shared__ float sPs[4];
    if (lane == 0) sPs[w] = ps;
    __syncthreads();
    if (tid == 0) psq[c] = sPs[0] + sPs[1] + sPs[2] + sPs[3];
}

// ---------------------------------------------------------------------------
// Kernel 2: q_sq per query row. One wave per row; f32x4 loads; shuffle reduce.
// ---------------------------------------------------------------------------
__global__ __launch_bounds__(256) void qsq_kernel(
    const float* __restrict__ zq, float* __restrict__ qsq)
{
    const int w    = threadIdx.x >> 6;
    const int lane = threadIdx.x & 63;
    const int row  = blockIdx.x * 4 + w;
    const f32x4* zp = (const f32x4*)(zq + (size_t)row * D_DIM);
    f32x4 a = zp[lane];
    f32x4 b = zp[64 + lane];
    float s = a.x*a.x + a.y*a.y + a.z*a.z + a.w*a.w
            + b.x*b.x + b.y*b.y + b.z*b.z + b.w*b.w;
    #pragma unroll
    for (int off = 32; off > 0; off >>= 1) s += __shfl_down(s, off, 64);
    if (lane == 0) qsq[row] = s;
}

// ---------------------------------------------------------------------------
// Kernel 3: GEMM  out[m][n] = 2*(q_m . p_n) - qsq[m] - psq[n]
// A = z_query f32 [M][K] (converted to bf16 during staging),
// B = protos bf16 [N][K] (B^T layout).  128x128 tile, BK=32, 4 waves 2x2,
// each wave 4x4 subtiles of mfma_f32_16x16x32_bf16 (m97 structure).
// ---------------------------------------------------------------------------
__global__ __launch_bounds__(256) void gemm_kernel(
    const float* __restrict__ A, const unsigned short* __restrict__ Bp,
    const float* __restrict__ qsq, const float* __restrict__ psq,
    float* __restrict__ out)
{
    constexpr int BM = 128, BN = 128, BK = 32, K = D_DIM, NN = C_CLASSES;
    __shared__ __align__(16) unsigned short shA[BM * BK];
    __shared__ __align__(16) unsigned short shB[BN * BK];

    const int tid  = threadIdx.x;
    const int lane = tid & 63;
    const int w    = tid >> 6;
    const int wm   = w >> 1, wn = w & 1;
    const int quad = lane >> 4, l16 = lane & 15;
    const int mBase = blockIdx.y * BM;
    const int nBase = blockIdx.x * BN;

    // staging maps
    const int arow = tid >> 3, achunk = tid & 7;  // A: 32 rows x 8 chunks of 4 f32
    const int brow = tid >> 2, bchunk = tid & 3;  // B: 64 rows x 4 chunks of 8 bf16

    f32x4 acc[4][4];
    #pragma unroll
    for (int i = 0; i < 4; i++)
        #pragma unroll
        for (int j = 0; j < 4; j++)
            acc[i][j] = (f32x4){0.f, 0.f, 0.f, 0.f};

    for (int k0 = 0; k0 < K; k0 += BK) {
        __syncthreads();
        // stage A: f32 global -> bf16 LDS
        #pragma unroll
        for (int r = 0; r < 4; r++) {
            int row = arow + r * 32;
            f32x4 v = *(const f32x4*)(A + (size_t)(mBase + row) * K + k0 + achunk * 4);
            u16x4 p;
            p.x = f2bf(v.x); p.y = f2bf(v.y); p.z = f2bf(v.z); p.w = f2bf(v.w);
            *(u16x4*)(&shA[row * BK + achunk * 4]) = p;
        }
        // stage B: bf16 global -> LDS (16B vector copies)
        #pragma unroll
        for (int r = 0; r < 2; r++) {
            int row = brow + r * 64;
            *(u16x8*)(&shB[row * BK + bchunk * 8]) =
                *(const u16x8*)(Bp + (size_t)(nBase + row) * K + k0 + bchunk * 8);
        }
        __syncthreads();

        bf16x8 af[4], bfr[4];
        #pragma unroll
        for (int i = 0; i < 4; i++) {
            af[i]  = *(const bf16x8*)&shA[(wm * 64 + i * 16 + l16) * BK + quad * 8];
            bfr[i] = *(const bf16x8*)&shB[(wn * 64 + i * 16 + l16) * BK + quad * 8];
        }
        #pragma unroll
        for (int i = 0; i < 4; i++)
            #pragma unroll
            for (int j = 0; j < 4; j++)
                acc[i][j] = __builtin_amdgcn_mfma_f32_16x16x32_bf16(
                    af[i], bfr[j], acc[i][j], 0, 0, 0);
    }

    // epilogue: out = 2*acc - qsq[row] - psq[col]
    const int rowb = mBase + wm * 64;
    const int colb = nBase + wn * 64;
    float pvv[4];
    #pragma unroll
    for (int j = 0; j < 4; j++) pvv[j] = psq[colb + j * 16 + l16];
    #pragma unroll
    for (int i = 0; i < 4; i++) {
        #pragma unroll
        for (int r = 0; r < 4; r++) {
            int rowg = rowb + i * 16 + quad * 4 + r;
            float qv = qsq[rowg];
            #pragma unroll
            for (int j = 0; j < 4; j++) {
                int col = colb + j * 16 + l16;
                out[(size_t)rowg * NN + col] = 2.0f * acc[i][j][r] - qv - pvv[j];
            }
        }
    }
}

extern "C" void kernel_launch(void* const* d_in, const int* in_sizes, int n_in,
                              void* d_out, int out_size, void* d_ws, size_t ws_size,
                              hipStream_t stream) {
    const float* zs = (const float*)d_in[0];
    const int*   ys = (const int*)d_in[1];
    const float* zq = (const float*)d_in[2];
    float* out = (float*)d_out;

    char* ws = (char*)d_ws;
    unsigned short* protos = (unsigned short*)ws;                       // 1 MiB
    float* psq = (float*)(ws + (size_t)C_CLASSES * D_DIM * 2);          // 4 KiB
    float* qsq = (float*)(ws + (size_t)C_CLASSES * D_DIM * 2 + 4096);   // 256 KiB

    proto_kernel<<<C_CLASSES, 256, 0, stream>>>(zs, ys, protos, psq);
    qsq_kernel<<<N_QRY / 4, 256, 0, stream>>>(zq, qsq);
    gemm_kernel<<<dim3(C_CLASSES / 128, N_QRY / 128), 256, 0, stream>>>(
        zq, protos, qsq, psq, out);
}

// Round 2
// 566.302 us; speedup vs baseline: 1.1775x; 1.1775x over previous
//
#include <hip/hip_runtime.h>
#include <stdint.h>

#define C_CLASSES 1024
#define D_DIM     512
#define N_SUP     65536
#define N_QRY     65536
#define SLOTS     144   // per-class row-list capacity (mean 64, sd ~8 -> 10 sd margin)

typedef float f32x4 __attribute__((ext_vector_type(4)));
typedef short bf16x8 __attribute__((ext_vector_type(8)));
typedef unsigned short u16x4 __attribute__((ext_vector_type(4)));
typedef unsigned short u16x8 __attribute__((ext_vector_type(8)));

#define GLOBAL_AS __attribute__((address_space(1)))
#define LDS_AS    __attribute__((address_space(3)))

__device__ inline void async_copy16(const void* g, void* l) {
    __builtin_amdgcn_global_load_lds((const GLOBAL_AS void*)g, (LDS_AS void*)l, 16, 0, 0);
}

// f32 -> bf16 round-to-nearest-even
__device__ inline unsigned short f2bf(float f) {
    union { float f; unsigned int u; } x; x.f = f;
    unsigned int u = x.u;
    return (unsigned short)((u + 0x7fffu + ((u >> 16) & 1u)) >> 16);
}

// ---------------------------------------------------------------------------
// Proto phase 0: zero class cursors (ws is poisoned 0xAA before every call).
// ---------------------------------------------------------------------------
__global__ void init_kernel(int* __restrict__ cursors) {
    cursors[threadIdx.x] = 0;
}

// ---------------------------------------------------------------------------
// Proto phase 1: counting-sort scatter. One thread per support row.
// ---------------------------------------------------------------------------
__global__ __launch_bounds__(256) void scatter_kernel(
    const int* __restrict__ ys, int* __restrict__ cursors, int* __restrict__ rowlist)
{
    int i = blockIdx.x * 256 + threadIdx.x;
    int c = ys[i];
    int slot = atomicAdd(&cursors[c], 1);
    if (slot < SLOTS) rowlist[c * SLOTS + slot] = i;
}

// ---------------------------------------------------------------------------
// Proto phase 2: gather + mean. One block per class, 4 waves split the list.
// Emits protos bf16 [C][D] (B^T layout) and p_sq f32 [C].
// ---------------------------------------------------------------------------
__global__ __launch_bounds__(256) void proto_gather(
    const float* __restrict__ zs, const int* __restrict__ rowlist,
    const int* __restrict__ cursors, unsigned short* __restrict__ protos,
    float* __restrict__ psq)
{
    const int c    = blockIdx.x;
    const int tid  = threadIdx.x;
    const int w    = tid >> 6;
    const int lane = tid & 63;

    const int cnt = cursors[c];
    const int m   = cnt < SLOTS ? cnt : SLOTS;

    f32x4 s0 = {0.f, 0.f, 0.f, 0.f};
    f32x4 s1 = {0.f, 0.f, 0.f, 0.f};
    for (int j = w; j < m; j += 4) {
        int r = rowlist[c * SLOTS + j];
        const f32x4* zp = (const f32x4*)(zs + (size_t)r * D_DIM);
        s0 += zp[lane];
        s1 += zp[64 + lane];
    }

    __shared__ float sAcc[4][D_DIM];
    ((f32x4*)&sAcc[w][0])[lane]      = s0;
    ((f32x4*)&sAcc[w][0])[64 + lane] = s1;
    __syncthreads();

    float inv = 1.0f / fmaxf((float)cnt, 1.0f);
    int t2 = tid + 256;
    float p0 = (sAcc[0][tid] + sAcc[1][tid] + sAcc[2][tid] + sAcc[3][tid]) * inv;
    float p1 = (sAcc[0][t2]  + sAcc[1][t2]  + sAcc[2][t2]  + sAcc[3][t2])  * inv;
    protos[(size_t)c * D_DIM + tid] = f2bf(p0);
    protos[(size_t)c * D_DIM + t2]  = f2bf(p1);

    float ps = p0 * p0 + p1 * p1;
    #pragma unroll
    for (int off = 32; off > 0; off >>= 1) ps += __shfl_down(ps, off, 64);
    __shared__ float sPs[4];
    if (lane == 0) sPs[w] = ps;
    __syncthreads();
    if (tid == 0) psq[c] = sPs[0] + sPs[1] + sPs[2] + sPs[3];
}

// ---------------------------------------------------------------------------
// q_sq + (optionally) one-pass f32->bf16 conversion of z_query into ws.
// One wave per row; lane covers 8 contiguous elems -> one 16B bf16 store.
// ---------------------------------------------------------------------------
template<bool CONV>
__global__ __launch_bounds__(256) void qsq_conv_kernel(
    const float* __restrict__ zq, float* __restrict__ qsq,
    unsigned short* __restrict__ Abf)
{
    const int w    = threadIdx.x >> 6;
    const int lane = threadIdx.x & 63;
    const int row  = blockIdx.x * 4 + w;
    const f32x4* zp = (const f32x4*)(zq + (size_t)row * D_DIM);
    f32x4 a = zp[2 * lane];
    f32x4 b = zp[2 * lane + 1];
    if (CONV) {
        u16x8 p;
        p.s0 = f2bf(a.x); p.s1 = f2bf(a.y); p.s2 = f2bf(a.z); p.s3 = f2bf(a.w);
        p.s4 = f2bf(b.x); p.s5 = f2bf(b.y); p.s6 = f2bf(b.z); p.s7 = f2bf(b.w);
        *(u16x8*)(Abf + (size_t)row * D_DIM + lane * 8) = p;
    }
    float s = a.x*a.x + a.y*a.y + a.z*a.z + a.w*a.w
            + b.x*b.x + b.y*b.y + b.z*b.z + b.w*b.w;
    #pragma unroll
    for (int off = 32; off > 0; off >>= 1) s += __shfl_down(s, off, 64);
    if (lane == 0) qsq[row] = s;
}

// ---------------------------------------------------------------------------
// GEMM: out[m][n] = 2*(q_m . p_n) - qsq[m] - psq[n]
// 128x128 tile, BK=32, 4 waves 2x2, 4x4 subtiles of mfma_f32_16x16x32_bf16.
// FAST: A staged via global_load_lds from pre-converted bf16 (m97 structure).
// ---------------------------------------------------------------------------
template<bool FAST>
__global__ __launch_bounds__(256) void gemm_kernel(
    const float* __restrict__ A32, const unsigned short* __restrict__ Abf,
    const unsigned short* __restrict__ Bp,
    const float* __restrict__ qsq, const float* __restrict__ psq,
    float* __restrict__ out)
{
    constexpr int BM = 128, BN = 128, BK = 32, K = D_DIM, NN = C_CLASSES;
    __shared__ __align__(16) unsigned short shA[BM * BK];
    __shared__ __align__(16) unsigned short shB[BN * BK];

    const int tid  = threadIdx.x;
    const int lane = tid & 63;
    const int w    = tid >> 6;
    const int wm   = w >> 1, wn = w & 1;
    const int quad = lane >> 4, l16 = lane & 15;
    const int mBase = blockIdx.y * BM;
    const int nBase = blockIdx.x * BN;

    // fallback A-staging map: 32 rows x 8 chunks of 4 f32
    const int arow = tid >> 3, achunk = tid & 7;
    // async staging map: lane -> row lane>>2, 16B chunk lane&3 (rows of 64B)
    const int srow = lane >> 2, schunk = (lane & 3) * 8;

    f32x4 acc[4][4];
    #pragma unroll
    for (int i = 0; i < 4; i++)
        #pragma unroll
        for (int j = 0; j < 4; j++)
            acc[i][j] = (f32x4){0.f, 0.f, 0.f, 0.f};

    for (int k0 = 0; k0 < K; k0 += BK) {
        __syncthreads();
        if (FAST) {
            #pragma unroll
            for (int t = 0; t < 2; t++) {
                int ci = w * 2 + t;            // 8 chunks of 16 rows
                async_copy16(Abf + (size_t)(mBase + ci * 16 + srow) * K + k0 + schunk,
                             &shA[ci * 16 * BK]);
                async_copy16(Bp  + (size_t)(nBase + ci * 16 + srow) * K + k0 + schunk,
                             &shB[ci * 16 * BK]);
            }
        } else {
            #pragma unroll
            for (int r = 0; r < 4; r++) {
                int row = arow + r * 32;
                f32x4 v = *(const f32x4*)(A32 + (size_t)(mBase + row) * K + k0 + achunk * 4);
                u16x4 p;
                p.x = f2bf(v.x); p.y = f2bf(v.y); p.z = f2bf(v.z); p.w = f2bf(v.w);
                *(u16x4*)(&shA[row * BK + achunk * 4]) = p;
            }
            #pragma unroll
            for (int t = 0; t < 2; t++) {
                int ci = w * 2 + t;
                async_copy16(Bp + (size_t)(nBase + ci * 16 + srow) * K + k0 + schunk,
                             &shB[ci * 16 * BK]);
            }
        }
        __syncthreads();

        bf16x8 af[4], bfr[4];
        #pragma unroll
        for (int i = 0; i < 4; i++) {
            af[i]  = *(const bf16x8*)&shA[(wm * 64 + i * 16 + l16) * BK + quad * 8];
            bfr[i] = *(const bf16x8*)&shB[(wn * 64 + i * 16 + l16) * BK + quad * 8];
        }
        #pragma unroll
        for (int i = 0; i < 4; i++)
            #pragma unroll
            for (int j = 0; j < 4; j++)
                acc[i][j] = __builtin_amdgcn_mfma_f32_16x16x32_bf16(
                    af[i], bfr[j], acc[i][j], 0, 0, 0);
    }

    // epilogue: out = 2*acc - qsq[row] - psq[col]
    const int rowb = mBase + wm * 64;
    const int colb = nBase + wn * 64;
    float pvv[4];
    #pragma unroll
    for (int j = 0; j < 4; j++) pvv[j] = psq[colb + j * 16 + l16];
    #pragma unroll
    for (int i = 0; i < 4; i++) {
        #pragma unroll
        for (int r = 0; r < 4; r++) {
            int rowg = rowb + i * 16 + quad * 4 + r;
            float qv = qsq[rowg];
            #pragma unroll
            for (int j = 0; j < 4; j++) {
                int col = colb + j * 16 + l16;
                out[(size_t)rowg * NN + col] = 2.0f * acc[i][j][r] - qv - pvv[j];
            }
        }
    }
}

extern "C" void kernel_launch(void* const* d_in, const int* in_sizes, int n_in,
                              void* d_out, int out_size, void* d_ws, size_t ws_size,
                              hipStream_t stream) {
    const float* zs = (const float*)d_in[0];
    const int*   ys = (const int*)d_in[1];
    const float* zq = (const float*)d_in[2];
    float* out = (float*)d_out;

    const size_t szAbf     = (size_t)N_QRY * D_DIM * 2;       // 64 MiB
    const size_t szProtos  = (size_t)C_CLASSES * D_DIM * 2;   // 1 MiB
    const size_t szQsq     = (size_t)N_QRY * 4;               // 256 KiB
    const size_t szRowlist = (size_t)C_CLASSES * SLOTS * 4;   // 576 KiB
    const size_t szPsq     = 4096;
    const size_t szCur     = 4096;

    const size_t needFast = szAbf + szProtos + szQsq + szRowlist + szPsq + szCur;
    const bool fast = ws_size >= needFast;

    char* ws = (char*)d_ws;
    unsigned short* Abf = (unsigned short*)ws;                 // fast path only
    char* base = fast ? ws + szAbf : ws;
    unsigned short* protos = (unsigned short*)base;
    float* qsq  = (float*)(base + szProtos);
    int*   rowlist = (int*)(base + szProtos + szQsq);
    float* psq  = (float*)(base + szProtos + szQsq + szRowlist);
    int*   cursors = (int*)(base + szProtos + szQsq + szRowlist + szPsq);

    init_kernel<<<1, C_CLASSES, 0, stream>>>(cursors);
    scatter_kernel<<<N_SUP / 256, 256, 0, stream>>>(ys, cursors, rowlist);
    if (fast)
        qsq_conv_kernel<true><<<N_QRY / 4, 256, 0, stream>>>(zq, qsq, Abf);
    else
        qsq_conv_kernel<false><<<N_QRY / 4, 256, 0, stream>>>(zq, qsq, nullptr);
    proto_gather<<<C_CLASSES, 256, 0, stream>>>(zs, rowlist, cursors, protos, psq);
    if (fast)
        gemm_kernel<true><<<dim3(C_CLASSES / 128, N_QRY / 128), 256, 0, stream>>>(
            nullptr, Abf, protos, qsq, psq, out);
    else
        gemm_kernel<false><<<dim3(C_CLASSES / 128, N_QRY / 128), 256, 0, stream>>>(
            zq, nullptr, protos, qsq, psq, out);
}

// Round 3
// 558.582 us; speedup vs baseline: 1.1938x; 1.0138x over previous
//
#include <hip/hip_runtime.h>
#include <stdint.h>

#define C_CLASSES 1024
#define D_DIM     512
#define N_SUP     65536
#define N_QRY     65536
#define SLOTS     144   // per-class row-list capacity (mean 64, sd ~8 -> 10 sd margin)

typedef float f32x4 __attribute__((ext_vector_type(4)));
typedef float f32x16v __attribute__((ext_vector_type(16)));
typedef short bf16x8 __attribute__((ext_vector_type(8)));
typedef unsigned short u16x4 __attribute__((ext_vector_type(4)));
typedef unsigned short u16x8 __attribute__((ext_vector_type(8)));

#define GLOBAL_AS __attribute__((address_space(1)))
#define LDS_AS    __attribute__((address_space(3)))

__device__ inline void async_copy16(const void* g, void* l) {
    __builtin_amdgcn_global_load_lds((const GLOBAL_AS void*)g, (LDS_AS void*)l, 16, 0, 0);
}

// f32 -> bf16 round-to-nearest-even
__device__ inline unsigned short f2bf(float f) {
    union { float f; unsigned int u; } x; x.f = f;
    unsigned int u = x.u;
    return (unsigned short)((u + 0x7fffu + ((u >> 16) & 1u)) >> 16);
}

// ---------------------------------------------------------------------------
// Phase 0: zero class cursors (ws is poisoned 0xAA before every call).
// ---------------------------------------------------------------------------
__global__ void init_kernel(int* __restrict__ cursors) {
    cursors[threadIdx.x] = 0;
}

// ---------------------------------------------------------------------------
// Phase 1: q_sq per query row + f32->bf16 conversion of z_query into ws,
// with the counting-sort scatter fused into blocks 0..255.
// ---------------------------------------------------------------------------
template<bool CONV>
__global__ __launch_bounds__(256) void qsq_conv_kernel(
    const float* __restrict__ zq, float* __restrict__ qsq,
    unsigned short* __restrict__ Abf,
    const int* __restrict__ ys, int* __restrict__ cursors,
    int* __restrict__ rowlist)
{
    // fused scatter: 256 blocks x 256 threads cover all support rows
    if (blockIdx.x < N_SUP / 256) {
        int i = blockIdx.x * 256 + threadIdx.x;
        int c = ys[i];
        int slot = atomicAdd(&cursors[c], 1);
        if (slot < SLOTS) rowlist[c * SLOTS + slot] = i;
    }

    const int w    = threadIdx.x >> 6;
    const int lane = threadIdx.x & 63;
    const int row  = blockIdx.x * 4 + w;
    const f32x4* zp = (const f32x4*)(zq + (size_t)row * D_DIM);
    f32x4 a = zp[2 * lane];
    f32x4 b = zp[2 * lane + 1];
    if (CONV) {
        u16x8 p;
        p.s0 = f2bf(a.x); p.s1 = f2bf(a.y); p.s2 = f2bf(a.z); p.s3 = f2bf(a.w);
        p.s4 = f2bf(b.x); p.s5 = f2bf(b.y); p.s6 = f2bf(b.z); p.s7 = f2bf(b.w);
        *(u16x8*)(Abf + (size_t)row * D_DIM + lane * 8) = p;
    }
    float s = a.x*a.x + a.y*a.y + a.z*a.z + a.w*a.w
            + b.x*b.x + b.y*b.y + b.z*b.z + b.w*b.w;
    #pragma unroll
    for (int off = 32; off > 0; off >>= 1) s += __shfl_down(s, off, 64);
    if (lane == 0) qsq[row] = s;
}

// ---------------------------------------------------------------------------
// Phase 2: gather + mean. One block per class, 4 waves split the list.
// Emits protos bf16 [C][D] (B^T layout) and p_sq f32 [C].
// ---------------------------------------------------------------------------
__global__ __launch_bounds__(256) void proto_gather(
    const float* __restrict__ zs, const int* __restrict__ rowlist,
    const int* __restrict__ cursors, unsigned short* __restrict__ protos,
    float* __restrict__ psq)
{
    const int c    = blockIdx.x;
    const int tid  = threadIdx.x;
    const int w    = tid >> 6;
    const int lane = tid & 63;

    const int cnt = cursors[c];
    const int m   = cnt < SLOTS ? cnt : SLOTS;

    f32x4 s0 = {0.f, 0.f, 0.f, 0.f};
    f32x4 s1 = {0.f, 0.f, 0.f, 0.f};
    for (int j = w; j < m; j += 4) {
        int r = rowlist[c * SLOTS + j];
        const f32x4* zp = (const f32x4*)(zs + (size_t)r * D_DIM);
        s0 += zp[lane];
        s1 += zp[64 + lane];
    }

    __shared__ float sAcc[4][D_DIM];
    ((f32x4*)&sAcc[w][0])[lane]      = s0;
    ((f32x4*)&sAcc[w][0])[64 + lane] = s1;
    __syncthreads();

    float inv = 1.0f / fmaxf((float)cnt, 1.0f);
    int t2 = tid + 256;
    float p0 = (sAcc[0][tid] + sAcc[1][tid] + sAcc[2][tid] + sAcc[3][tid]) * inv;
    float p1 = (sAcc[0][t2]  + sAcc[1][t2]  + sAcc[2][t2]  + sAcc[3][t2])  * inv;
    protos[(size_t)c * D_DIM + tid] = f2bf(p0);
    protos[(size_t)c * D_DIM + t2]  = f2bf(p1);

    float ps = p0 * p0 + p1 * p1;
    #pragma unroll
    for (int off = 32; off > 0; off >>= 1) ps += __shfl_down(ps, off, 64);
    __shared__ float sPs[4];
    if (lane == 0) sPs[w] = ps;
    __syncthreads();
    if (tid == 0) psq[c] = sPs[0] + sPs[1] + sPs[2] + sPs[3];
}

// ---------------------------------------------------------------------------
// Phase 3: GEMM  out[m][n] = 2*(q_m . p_n) - qsq[m] - psq[n]
// 128x128 block, BK=32, 4 waves 2x2 (wave = 64x64), 2x2 subtiles of
// mfma_f32_32x32x16_bf16.  LDS chunks XOR-swizzled (slot = c ^ ((r>>1)&3))
// so the 32-lane-per-chunk b128 fragment reads hit all 32 banks balanced.
// async global_load_lds staging (we permute which global chunk each lane
// fetches; the LDS destination slot is fixed by the instruction).
// ---------------------------------------------------------------------------
template<bool FAST>
__global__ __launch_bounds__(256) void gemm_kernel(
    const float* __restrict__ A32, const unsigned short* __restrict__ Abf,
    const unsigned short* __restrict__ Bp,
    const float* __restrict__ qsq, const float* __restrict__ psq,
    float* __restrict__ out)
{
    constexpr int BM = 128, BN = 128, BK = 32, K = D_DIM, NN = C_CLASSES;
    __shared__ __align__(16) unsigned short shA[BM * BK];
    __shared__ __align__(16) unsigned short shB[BN * BK];

    const int tid  = threadIdx.x;
    const int lane = tid & 63;
    const int w    = tid >> 6;
    const int wm   = w >> 1, wn = w & 1;
    const int l31  = lane & 31, half = lane >> 5;
    const int mBase = blockIdx.y * BM;
    const int nBase = blockIdx.x * BN;

    // async staging map: lane -> row lane>>2 within 16-row group, slot lane&3
    const int srow = lane >> 2;
    const int sx   = lane & 3;
    const int scg  = (sx ^ ((srow >> 1) & 3)) * 8;  // swizzled global chunk (elems)

    f32x16v acc[2][2];
    #pragma unroll
    for (int i = 0; i < 2; i++)
        #pragma unroll
        for (int j = 0; j < 2; j++)
            acc[i][j] = (f32x16v)(0.0f);

    for (int k0 = 0; k0 < K; k0 += BK) {
        __syncthreads();
        if (FAST) {
            #pragma unroll
            for (int t = 0; t < 2; t++) {
                int ci = w * 2 + t;            // 8 groups of 16 rows
                async_copy16(Abf + (size_t)(mBase + ci * 16 + srow) * K + k0 + scg,
                             &shA[ci * 16 * BK]);
                async_copy16(Bp  + (size_t)(nBase + ci * 16 + srow) * K + k0 + scg,
                             &shB[ci * 16 * BK]);
            }
        } else {
            // stage A from f32 with conversion, honoring the swizzle
            #pragma unroll
            for (int t = 0; t < 2; t++) {
                int q = tid * 2 + t;          // chunk id 0..511
                int r = q >> 2;               // row 0..127
                int x = q & 3;                // LDS slot
                int cg = x ^ ((r >> 1) & 3);
                const float* src = A32 + (size_t)(mBase + r) * K + k0 + cg * 8;
                f32x4 v0 = *(const f32x4*)src;
                f32x4 v1 = *(const f32x4*)(src + 4);
                u16x8 p;
                p.s0 = f2bf(v0.x); p.s1 = f2bf(v0.y); p.s2 = f2bf(v0.z); p.s3 = f2bf(v0.w);
                p.s4 = f2bf(v1.x); p.s5 = f2bf(v1.y); p.s6 = f2bf(v1.z); p.s7 = f2bf(v1.w);
                *(u16x8*)&shA[r * BK + x * 8] = p;
            }
            #pragma unroll
            for (int t = 0; t < 2; t++) {
                int ci = w * 2 + t;
                async_copy16(Bp + (size_t)(nBase + ci * 16 + srow) * K + k0 + scg,
                             &shB[ci * 16 * BK]);
            }
        }
        __syncthreads();

        // fragments: A row = m (l31), k = ks*16 + half*8 + j
        bf16x8 af[2][2], bfv[2][2];
        #pragma unroll
        for (int i = 0; i < 2; i++) {
            int ra = wm * 64 + i * 32 + l31;
            int ga = (ra >> 1) & 3;
            int rb = wn * 64 + i * 32 + l31;
            int gb = (rb >> 1) & 3;
            #pragma unroll
            for (int ks = 0; ks < 2; ks++) {
                int c = ks * 2 + half;
                af[i][ks]  = *(const bf16x8*)&shA[ra * BK + ((c ^ ga) * 8)];
                bfv[i][ks] = *(const bf16x8*)&shB[rb * BK + ((c ^ gb) * 8)];
            }
        }
        #pragma unroll
        for (int ks = 0; ks < 2; ks++)
            #pragma unroll
            for (int i = 0; i < 2; i++)
                #pragma unroll
                for (int j = 0; j < 2; j++)
                    acc[i][j] = __builtin_amdgcn_mfma_f32_32x32x16_bf16(
                        af[i][ks], bfv[j][ks], acc[i][j], 0, 0, 0);
    }

    // epilogue: out = 2*acc - qsq[row] - psq[col]
    // C/D layout (verified m74/m101): col = lane&31, row = (reg&3)+8*(reg>>2)+4*half
    const int rowb = mBase + wm * 64;
    const int colb = nBase + wn * 64;
    float pv[2];
    #pragma unroll
    for (int j = 0; j < 2; j++) pv[j] = psq[colb + j * 32 + l31];
    #pragma unroll
    for (int i = 0; i < 2; i++) {
        #pragma unroll
        for (int rg = 0; rg < 4; rg++) {
            int rbase = rowb + i * 32 + rg * 8 + half * 4;
            f32x4 qv = *(const f32x4*)&qsq[rbase];
            #pragma unroll
            for (int rr = 0; rr < 4; rr++) {
                int reg = rg * 4 + rr;
                size_t rowoff = (size_t)(rbase + rr) * NN;
                #pragma unroll
                for (int j = 0; j < 2; j++) {
                    out[rowoff + colb + j * 32 + l31] =
                        2.0f * acc[i][j][reg] - qv[rr] - pv[j];
                }
            }
        }
    }
}

extern "C" void kernel_launch(void* const* d_in, const int* in_sizes, int n_in,
                              void* d_out, int out_size, void* d_ws, size_t ws_size,
                              hipStream_t stream) {
    const float* zs = (const float*)d_in[0];
    const int*   ys = (const int*)d_in[1];
    const float* zq = (const float*)d_in[2];
    float* out = (float*)d_out;

    const size_t szAbf     = (size_t)N_QRY * D_DIM * 2;       // 64 MiB
    const size_t szProtos  = (size_t)C_CLASSES * D_DIM * 2;   // 1 MiB
    const size_t szQsq     = (size_t)N_QRY * 4;               // 256 KiB
    const size_t szRowlist = (size_t)C_CLASSES * SLOTS * 4;   // 576 KiB
    const size_t szPsq     = 4096;
    const size_t szCur     = 4096;

    const size_t needFast = szAbf + szProtos + szQsq + szRowlist + szPsq + szCur;
    const bool fast = ws_size >= needFast;

    char* ws = (char*)d_ws;
    unsigned short* Abf = (unsigned short*)ws;                 // fast path only
    char* base = fast ? ws + szAbf : ws;
    unsigned short* protos = (unsigned short*)base;
    float* qsq  = (float*)(base + szProtos);
    int*   rowlist = (int*)(base + szProtos + szQsq);
    float* psq  = (float*)(base + szProtos + szQsq + szRowlist);
    int*   cursors = (int*)(base + szProtos + szQsq + szRowlist + szPsq);

    init_kernel<<<1, C_CLASSES, 0, stream>>>(cursors);
    if (fast)
        qsq_conv_kernel<true><<<N_QRY / 4, 256, 0, stream>>>(
            zq, qsq, Abf, ys, cursors, rowlist);
    else
        qsq_conv_kernel<false><<<N_QRY / 4, 256, 0, stream>>>(
            zq, qsq, nullptr, ys, cursors, rowlist);
    proto_gather<<<C_CLASSES, 256, 0, stream>>>(zs, rowlist, cursors, protos, psq);
    if (fast)
        gemm_kernel<true><<<dim3(C_CLASSES / 128, N_QRY / 128), 256, 0, stream>>>(
            nullptr, Abf, protos, qsq, psq, out);
    else
        gemm_kernel<false><<<dim3(C_CLASSES / 128, N_QRY / 128), 256, 0, stream>>>(
            zq, nullptr, protos, qsq, psq, out);
}